// Round 2
// baseline (202.254 us; speedup 1.0000x reference)
//
#include <hip/hip_runtime.h>

// Problem constants (from setup_inputs):
//   input_: (B=64, 2*N=16384, 2, 2, D1=16) f32
//   diag1/diag2: (N=8192, 2, 2, D2=8) f32
//   out: (B, N, 2, 2, DOUT=23) f32,  out[b,n,i,j,:] =
//        sum_k conv(x1[b,n,i,k,:], d1[n,k,j,:]) + sum_k conv(x2[b,n,i,k,:], d2[n,k,j,:])
#define BB 64
#define NN 8192
#define D1C 16
#define D2C 8
#define DOUT 23

__device__ __forceinline__ void accum_half(const float4* __restrict__ x4,
                                           const float4* __restrict__ d4,
                                           float acc[2][2][DOUT]) {
    // Load diag block: 32 floats, layout [k][j][v], v innermost (8 per (k,j))
    float dd[2][2][D2C];
#pragma unroll
    for (int q = 0; q < 8; ++q) {
        float4 t = d4[q];
        const int k = q >> 2;
        const int j = (q >> 1) & 1;
        const int h = (q & 1) * 4;
        dd[k][j][h + 0] = t.x;
        dd[k][j][h + 1] = t.y;
        dd[k][j][h + 2] = t.z;
        dd[k][j][h + 3] = t.w;
    }

#pragma unroll
    for (int i = 0; i < 2; ++i) {
#pragma unroll
        for (int k = 0; k < 2; ++k) {
            // x row: 16 floats, layout [i][k][u]
            float xv[D1C];
#pragma unroll
            for (int q = 0; q < 4; ++q) {
                float4 t = x4[(i * 2 + k) * 4 + q];
                xv[q * 4 + 0] = t.x;
                xv[q * 4 + 1] = t.y;
                xv[q * 4 + 2] = t.z;
                xv[q * 4 + 3] = t.w;
            }
#pragma unroll
            for (int j = 0; j < 2; ++j) {
#pragma unroll
                for (int v = 0; v < D2C; ++v) {
                    const float c = dd[k][j][v];
#pragma unroll
                    for (int u = 0; u < D1C; ++u) {
                        acc[i][j][u + v] += xv[u] * c;
                    }
                }
            }
        }
    }
}

__global__ __launch_bounds__(256) void hstackdiag_kernel(
    const float* __restrict__ input,
    const float* __restrict__ diag1,
    const float* __restrict__ diag2,
    float* __restrict__ out) {
    const int idx = blockIdx.x * blockDim.x + threadIdx.x;  // linear (b, n)
    const int n = idx & (NN - 1);

    // Per-(b,n) input block: 64 contiguous floats ([i][k][u]); second half at +N rows.
    const float4* x1 = (const float4*)input + (size_t)(idx >> 13) * (2 * NN) * 16 + (size_t)n * 16;
    const float4* x2 = x1 + (size_t)NN * 16;
    const float4* d1 = (const float4*)diag1 + (size_t)n * 8;
    const float4* d2 = (const float4*)diag2 + (size_t)n * 8;

    float acc[2][2][DOUT];
#pragma unroll
    for (int i = 0; i < 2; ++i)
#pragma unroll
        for (int j = 0; j < 2; ++j)
#pragma unroll
            for (int u = 0; u < DOUT; ++u) acc[i][j][u] = 0.0f;

    accum_half(x1, d1, acc);
    accum_half(x2, d2, acc);

    // Write 92 contiguous floats = 23 aligned float4 (92*idx % 4 == 0).
    float4* o4 = (float4*)out + (size_t)idx * DOUT;
    const float* a = &acc[0][0][0];
#pragma unroll
    for (int q = 0; q < DOUT; ++q) {
        o4[q] = make_float4(a[q * 4 + 0], a[q * 4 + 1], a[q * 4 + 2], a[q * 4 + 3]);
    }
}

extern "C" void kernel_launch(void* const* d_in, const int* in_sizes, int n_in,
                              void* d_out, int out_size, void* d_ws, size_t ws_size,
                              hipStream_t stream) {
    const float* input = (const float*)d_in[0];
    const float* diag1 = (const float*)d_in[1];
    const float* diag2 = (const float*)d_in[2];
    float* out = (float*)d_out;

    const int total = BB * NN;           // 524288 threads, one per (b,n)
    const int block = 256;
    const int grid = total / block;      // 2048 blocks, exact
    hstackdiag_kernel<<<grid, block, 0, stream>>>(input, diag1, diag2, out);
}